// Round 1
// baseline (4960.137 us; speedup 1.0000x reference)
//
#include <hip/hip_runtime.h>
#include <math.h>

// Problem constants (from reference)
#define B_TOT  16384
#define DD     16      // theta dim
#define CTX    256
#define HID    192
#define NSTEPS 10
#define DT     (-0.1f)

// Tiling
#define ROWS 8         // batch rows per block
#define SROW 200       // padded LDS row stride (floats): bank offset 8/row -> <=2-way aliasing (free)

__device__ __forceinline__ void gelu_both(float x, float& gv, float& dv) {
    // exact (erf) GELU and its derivative, sharing the erf/exp
    float cdf = 0.5f * (1.0f + erff(x * 0.70710678118654752f));
    float pdf = 0.3989422804014327f * expf(-0.5f * x * x);
    gv = x * cdf;
    dv = cdf + x * pdf;
}

__global__ __launch_bounds__(HID) void cnf_kernel(
    const float* __restrict__ theta, const float* __restrict__ hctx,
    const float* __restrict__ eps,   const float* __restrict__ W1,
    const float* __restrict__ b1,    const float* __restrict__ W2,
    const float* __restrict__ b2,    const float* __restrict__ W3,
    const float* __restrict__ b3,    float* __restrict__ out)
{
    const int tid  = threadIdx.x;            // 0..191, owns hidden unit `tid`
    const int row0 = blockIdx.x * ROWS;

    __shared__ float c[ROWS][SROW];          // b1 + h @ W1[16:272]  (time-invariant)
    __shared__ float g[ROWS][SROW];          // h1 (then reused as h2)
    __shared__ float dg[ROWS][SROW];         // dh1 (then reused as dh2)
    __shared__ float ybase[ROWS][DD];
    __shared__ float ystage[ROWS][DD];
    __shared__ float ebuf[ROWS][DD];
    __shared__ float F[4][ROWS][DD];         // stage vector-field outputs
    __shared__ float TR[ROWS][DD];           // trace partial products
    __shared__ float trace_s[4][ROWS];
    __shared__ float logp_s[ROWS];

    // Per-thread invariant weights: W1 column `tid` for the y-rows (0..15) and t-row (272)
    float w1y[DD];
    #pragma unroll
    for (int d = 0; d < DD; ++d) w1y[d] = W1[d * HID + tid];
    const float w1t = W1[272 * HID + tid];
    const float b2v = b2[tid];

    // ---- Precompute c[r][tid] = b1[tid] + sum_i h[row][i] * W1[16+i][tid] ----
    {
        float acc[ROWS];
        #pragma unroll
        for (int r = 0; r < ROWS; ++r) acc[r] = b1[tid];
        #pragma unroll 4
        for (int i = 0; i < CTX; ++i) {
            float w = W1[(DD + i) * HID + tid];      // coalesced across block
            #pragma unroll
            for (int r = 0; r < ROWS; ++r)
                acc[r] += hctx[(row0 + r) * CTX + i] * w;  // uniform -> scalar loads
        }
        #pragma unroll
        for (int r = 0; r < ROWS; ++r) c[r][tid] = acc[r];
    }

    if (tid < ROWS * DD) {
        int r = tid / DD, d = tid % DD;
        ybase[r][d] = theta[(row0 + r) * DD + d];
    }
    if (tid < ROWS) logp_s[tid] = 0.0f;
    __syncthreads();

    for (int step = 0; step < NSTEPS; ++step) {
        const float t0 = 1.0f + DT * (float)step;

        for (int s = 0; s < 4; ++s) {
            // ---- stage input y and fresh Hutchinson noise ----
            if (tid < ROWS * DD) {
                int r = tid / DD, d = tid % DD;
                float y;
                if      (s == 0) y = ybase[r][d];
                else if (s == 1) y = ybase[r][d] + DT * F[0][r][d] * (1.0f / 3.0f);
                else if (s == 2) y = ybase[r][d] + DT * (F[1][r][d] - F[0][r][d] * (1.0f / 3.0f));
                else             y = ybase[r][d] + DT * (F[0][r][d] - F[1][r][d] + F[2][r][d]);
                ystage[r][d] = y;
                ebuf[r][d]   = eps[((step * 4 + s) * B_TOT + row0 + r) * DD + d];
            }
            __syncthreads();
            const float ts = (s == 0) ? t0
                           : (s == 1) ? t0 + DT * (1.0f / 3.0f)
                           : (s == 2) ? t0 + DT * (2.0f / 3.0f)
                           :            t0 + DT;

            // ---- layer 1: a1 = c + y@W1y + t*W1t ; da1 = e@W1y ----
            #pragma unroll
            for (int r = 0; r < ROWS; ++r) {
                float a  = c[r][tid] + ts * w1t;
                float da = 0.0f;
                #pragma unroll
                for (int d = 0; d < DD; ++d) {
                    a  += ystage[r][d] * w1y[d];
                    da += ebuf[r][d]   * w1y[d];
                }
                float gv, dv;
                gelu_both(a, gv, dv);
                g[r][tid]  = gv;
                dg[r][tid] = dv * da;
            }
            __syncthreads();

            // ---- layer 2: a2[k] = b2 + h1@W2 ; da2[k] = dh1@W2 (shared weight read) ----
            float a2[ROWS], da2[ROWS];
            #pragma unroll
            for (int r = 0; r < ROWS; ++r) { a2[r] = b2v; da2[r] = 0.0f; }
            #pragma unroll 4
            for (int j = 0; j < HID; ++j) {
                float w = W2[j * HID + tid];             // coalesced, L2-resident
                #pragma unroll
                for (int r = 0; r < ROWS; ++r) {
                    a2[r]  += g[r][j]  * w;              // LDS broadcast
                    da2[r] += dg[r][j] * w;
                }
            }
            __syncthreads();                              // reads of g/dg done
            #pragma unroll
            for (int r = 0; r < ROWS; ++r) {
                float gv, dv;
                gelu_both(a2[r], gv, dv);
                g[r][tid]  = gv;                          // now h2
                dg[r][tid] = dv * da2[r];                 // now dh2
            }
            __syncthreads();

            // ---- layer 3 + trace: threads 0..127 -> (r,d) ----
            if (tid < ROWS * DD) {
                int r = tid / DD, d = tid % DD;
                float f = b3[d], je = 0.0f;
                #pragma unroll 4
                for (int k = 0; k < HID; ++k) {
                    float w = W3[k * DD + d];
                    f  += g[r][k]  * w;
                    je += dg[r][k] * w;
                }
                F[s][r][d] = f;
                TR[r][d]   = ebuf[r][d] * je;
            }
            __syncthreads();
            if (tid < ROWS) {
                float tr = 0.0f;
                #pragma unroll
                for (int d = 0; d < DD; ++d) tr += TR[tid][d];
                trace_s[s][tid] = tr;
            }
            __syncthreads();
        }

        // ---- RK4 (3/8 rule) combine ----
        if (tid < ROWS * DD) {
            int r = tid / DD, d = tid % DD;
            ybase[r][d] += DT * (F[0][r][d] + 3.0f * (F[1][r][d] + F[2][r][d]) + F[3][r][d]) * 0.125f;
        }
        if (tid < ROWS) {
            float l1 = -trace_s[0][tid], l2 = -trace_s[1][tid];
            float l3 = -trace_s[2][tid], l4 = -trace_s[3][tid];
            logp_s[tid] += DT * (l1 + 3.0f * (l2 + l3) + l4) * 0.125f;
        }
        __syncthreads();
    }

    // ---- output: base log-prob minus accumulated divergence ----
    if (tid < ROWS) {
        float s2 = 0.0f;
        #pragma unroll
        for (int d = 0; d < DD; ++d) s2 += ybase[tid][d] * ybase[tid][d];
        float base = -0.5f * s2 - 14.7030165313f;   // 0.5*D*ln(2*pi), D=16
        out[row0 + tid] = base - logp_s[tid];
    }
}

extern "C" void kernel_launch(void* const* d_in, const int* in_sizes, int n_in,
                              void* d_out, int out_size, void* d_ws, size_t ws_size,
                              hipStream_t stream) {
    const float* theta = (const float*)d_in[0];
    const float* hctx  = (const float*)d_in[1];
    const float* eps   = (const float*)d_in[2];
    const float* W1    = (const float*)d_in[3];
    const float* b1    = (const float*)d_in[4];
    const float* W2    = (const float*)d_in[5];
    const float* b2    = (const float*)d_in[6];
    const float* W3    = (const float*)d_in[7];
    const float* b3    = (const float*)d_in[8];
    float* outp = (float*)d_out;

    dim3 grid(B_TOT / ROWS), block(HID);
    hipLaunchKernelGGL(cnf_kernel, grid, block, 0, stream,
                       theta, hctx, eps, W1, b1, W2, b2, W3, b3, outp);
}

// Round 2
// 480.275 us; speedup vs baseline: 10.3277x; 10.3277x over previous
//
#include <hip/hip_runtime.h>
#include <math.h>

// ConditionalCNF log_prob, MFMA version.
// Per block: 32 batch rows. M=64 MFMA rows = [32 fwd ; 32 tangent].
// Layer1: K=32 (y/e in k0..15, zero-pad), Layer2: K=192, Layer3: K=192,N=16.
// Weights repacked to B-fragment order (B[n=lane&15][k=quad*8+j]) in d_ws.

#define DTc (-0.1f)

typedef __attribute__((ext_vector_type(8))) short bf16x8;
typedef __attribute__((ext_vector_type(8))) unsigned short u16x8;
typedef __attribute__((ext_vector_type(4))) float f32x4;

#define MFMA16(a, b, c) __builtin_amdgcn_mfma_f32_16x16x32_bf16((a), (b), (c), 0, 0, 0)

__device__ __forceinline__ unsigned short f2bf(float x) {
    union { float f; unsigned int u; } c; c.f = x;
    unsigned int r = c.u + 0x7FFFu + ((c.u >> 16) & 1u);   // RNE
    return (unsigned short)(r >> 16);
}

__device__ __forceinline__ void gelu_both(float x, float& gv, float& dv) {
    // exact (erf) GELU + derivative
    float cdf = 0.5f * (1.0f + erff(x * 0.70710678118654752f));
    float pdf = 0.3989422804014327f * __expf(-0.5f * x * x);
    gv = x * cdf;
    dv = cdf + x * pdf;
}

// ---------------- weight repack: fp32 -> bf16 B-fragments in ws ----------------
// w2f : [kb(6)][nt(12)][lane(64)][8]   B[n][k]=W2[k][n]
// w1yf: [nt(12)][lane(64)][8]          k<16 -> W1[k][n], else 0
// w1cf: [kb(8)][nt(12)][lane(64)][8]   B[n][k]=W1[16+k][n]
// w3f : [kb(6)][lane(64)][8]           B[n][k]=W3[k][n], n=lane&15 (d)
__global__ void repack_kernel(const float* __restrict__ W1, const float* __restrict__ W2,
                              const float* __restrict__ W3,
                              unsigned short* __restrict__ w2f, unsigned short* __restrict__ w1yf,
                              unsigned short* __restrict__ w1cf, unsigned short* __restrict__ w3fg) {
    int t = blockIdx.x * 256 + threadIdx.x;
    u16x8 v;
    if (t < 4608) {
        int kb = t / 768, rem = t % 768, nt = rem / 64, lane = rem % 64;
        int n = nt * 16 + (lane & 15), k0 = kb * 32 + (lane >> 4) * 8;
        #pragma unroll
        for (int j = 0; j < 8; ++j) v[j] = f2bf(W2[(k0 + j) * 192 + n]);
        *(u16x8*)(w2f + t * 8) = v;
    } else if (t < 5376) {
        int i2 = t - 4608, nt = i2 / 64, lane = i2 % 64;
        int n = nt * 16 + (lane & 15), k0 = (lane >> 4) * 8;
        #pragma unroll
        for (int j = 0; j < 8; ++j) {
            int k = k0 + j;
            v[j] = (k < 16) ? f2bf(W1[k * 192 + n]) : (unsigned short)0;
        }
        *(u16x8*)(w1yf + i2 * 8) = v;
    } else if (t < 11520) {
        int i3 = t - 5376, kb = i3 / 768, rem = i3 % 768, nt = rem / 64, lane = rem % 64;
        int n = nt * 16 + (lane & 15), k0 = kb * 32 + (lane >> 4) * 8;
        #pragma unroll
        for (int j = 0; j < 8; ++j) v[j] = f2bf(W1[(16 + k0 + j) * 192 + n]);
        *(u16x8*)(w1cf + i3 * 8) = v;
    } else if (t < 11904) {
        int i4 = t - 11520, kb = i4 / 64, lane = i4 % 64;
        int n = lane & 15, k0 = kb * 32 + (lane >> 4) * 8;
        #pragma unroll
        for (int j = 0; j < 8; ++j) v[j] = f2bf(W3[(k0 + j) * 16 + n]);
        *(u16x8*)(w3fg + i4 * 8) = v;
    }
}

// ---------------- main kernel ----------------
__global__ __launch_bounds__(256, 2) void cnf_mfma(
    const float* __restrict__ theta, const float* __restrict__ hctx,
    const float* __restrict__ eps,   const float* __restrict__ W1,
    const float* __restrict__ b1,    const float* __restrict__ b2,
    const float* __restrict__ b3,
    const unsigned short* __restrict__ w2f, const unsigned short* __restrict__ w1yf,
    const unsigned short* __restrict__ w1cf, const unsigned short* __restrict__ w3fg,
    float* __restrict__ out)
{
    __shared__ __align__(16) unsigned short Y[64 * 40];    // layer1 A: rows 0..31 y, 32..63 e; k16..39 = 0
    __shared__ __align__(16) unsigned short Xa[64 * 200];  // activations (h1/dh1 then h2/dh2); aliased as Hs
    __shared__ __align__(16) float ebf[32 * 16];           // fp32 eps for trace

    const int tid  = threadIdx.x;
    const int wave = tid >> 6, lane = tid & 63;
    const int l15  = lane & 15, quad = lane >> 4;
    const int r0   = blockIdx.x * 32;
    const int ntg0 = wave * 3;   // this wave's first n-tile (of 12)

    // zero Y (pads must be 0 for layer-1 K-padding)
    for (int i = tid; i < 64 * 40; i += 256) Y[i] = 0;

    // stage h -> Hs (alias Xa), stride 264 bf16
    unsigned short* Hs = Xa;
    for (int i = tid; i < 32 * 256; i += 256) {
        int r = i >> 8, k = i & 255;
        Hs[r * 264 + k] = f2bf(hctx[(r0 + r) * 256 + k]);
    }

    // per-wave constant fragments / scalars
    bf16x8 b1yfr[3], w3fr[6];
    #pragma unroll
    for (int nt = 0; nt < 3; ++nt)
        b1yfr[nt] = *reinterpret_cast<const bf16x8*>(w1yf + ((ntg0 + nt) * 64 + lane) * 8);
    #pragma unroll
    for (int kb = 0; kb < 6; ++kb)
        w3fr[kb] = *reinterpret_cast<const bf16x8*>(w3fg + (kb * 64 + lane) * 8);
    float w1tr[3], b2r[3], b1r[3];
    #pragma unroll
    for (int nt = 0; nt < 3; ++nt) {
        int n = (ntg0 + nt) * 16 + l15;
        w1tr[nt] = W1[272 * 192 + n];
        b2r[nt]  = b2[n];
        b1r[nt]  = b1[n];
    }
    const float b3r = b3[l15];

    // wave 0 integration state: yreg[mt][i] = y[r = mt*16+quad*4+i][d = l15]
    float yreg[2][4];
    if (wave == 0) {
        #pragma unroll
        for (int mt = 0; mt < 2; ++mt)
            #pragma unroll
            for (int i = 0; i < 4; ++i)
                yreg[mt][i] = theta[(r0 + mt * 16 + quad * 4 + i) * 16 + l15];
    }

    __syncthreads();

    // ---- c = b1 + h @ W1ctx, kept in registers (D-frag mapping == layer-1 epilogue need) ----
    float cr[2][3][4];
    {
        f32x4 ca[2][3] = {};
        #pragma unroll
        for (int kb = 0; kb < 8; ++kb) {
            bf16x8 af[2];
            #pragma unroll
            for (int mt = 0; mt < 2; ++mt)
                af[mt] = *reinterpret_cast<const bf16x8*>(&Hs[(mt * 16 + l15) * 264 + kb * 32 + quad * 8]);
            #pragma unroll
            for (int nt = 0; nt < 3; ++nt) {
                bf16x8 bf = *reinterpret_cast<const bf16x8*>(w1cf + ((kb * 12 + ntg0 + nt) * 64 + lane) * 8);
                #pragma unroll
                for (int mt = 0; mt < 2; ++mt)
                    ca[mt][nt] = MFMA16(af[mt], bf, ca[mt][nt]);
            }
        }
        #pragma unroll
        for (int mt = 0; mt < 2; ++mt)
            #pragma unroll
            for (int nt = 0; nt < 3; ++nt)
                #pragma unroll
                for (int i = 0; i < 4; ++i)
                    cr[mt][nt][i] = ca[mt][nt][i] + b1r[nt];
    }

    float F1[2][4], F2[2][4], F3[2][4];
    float tracc[2][4] = {{0.f,0.f,0.f,0.f},{0.f,0.f,0.f,0.f}};

    for (int step = 0; step < 10; ++step) {
        const float t0 = 1.0f + DTc * (float)step;
        #pragma unroll
        for (int sub = 0; sub < 4; ++sub) {
            // ---- stage inputs: y (wave 0) and eps (all) into Y + ebf ----
            if (wave == 0) {
                #pragma unroll
                for (int mt = 0; mt < 2; ++mt)
                    #pragma unroll
                    for (int i = 0; i < 4; ++i) {
                        float ys = yreg[mt][i];
                        if (sub == 1) ys += DTc * (1.0f / 3.0f) * F1[mt][i];
                        else if (sub == 2) ys += DTc * (F2[mt][i] - (1.0f / 3.0f) * F1[mt][i]);
                        else if (sub == 3) ys += DTc * (F1[mt][i] - F2[mt][i] + F3[mt][i]);
                        Y[(mt * 16 + quad * 4 + i) * 40 + l15] = f2bf(ys);
                    }
            }
            {
                const int sg = step * 4 + sub;
                #pragma unroll
                for (int ii = 0; ii < 2; ++ii) {
                    int idx = tid + ii * 256;
                    int r = idx >> 4, d = idx & 15;
                    float v = eps[((long)sg * 16384 + r0 + r) * 16 + d];
                    ebf[r * 16 + d] = v;
                    Y[(32 + r) * 40 + d] = f2bf(v);
                }
            }
            __syncthreads();   // B1

            const float ts = t0 + DTc * (sub == 0 ? 0.0f : sub == 1 ? (1.0f/3.0f) : sub == 2 ? (2.0f/3.0f) : 1.0f);

            // ---- layer 1 (K=32) + GELU epilogue -> Xa ----
            {
                f32x4 acc[4][3] = {};
                bf16x8 af[4];
                #pragma unroll
                for (int mt = 0; mt < 4; ++mt)
                    af[mt] = *reinterpret_cast<const bf16x8*>(&Y[(mt * 16 + l15) * 40 + quad * 8]);
                #pragma unroll
                for (int nt = 0; nt < 3; ++nt)
                    #pragma unroll
                    for (int mt = 0; mt < 4; ++mt)
                        acc[mt][nt] = MFMA16(af[mt], b1yfr[nt], acc[mt][nt]);
                #pragma unroll
                for (int nt = 0; nt < 3; ++nt) {
                    int n = (ntg0 + nt) * 16 + l15;
                    #pragma unroll
                    for (int mt = 0; mt < 2; ++mt)
                        #pragma unroll
                        for (int i = 0; i < 4; ++i) {
                            float a = acc[mt][nt][i] + cr[mt][nt][i] + ts * w1tr[nt];
                            float gv, dv; gelu_both(a, gv, dv);
                            Xa[(mt * 16 + quad * 4 + i) * 200 + n] = f2bf(gv);
                            Xa[((mt + 2) * 16 + quad * 4 + i) * 200 + n] = f2bf(dv * acc[mt + 2][nt][i]);
                        }
                }
            }
            __syncthreads();   // B2

            // ---- layer 2 (K=192) ----
            f32x4 acc2[4][3] = {};
            #pragma unroll
            for (int kb = 0; kb < 6; ++kb) {
                bf16x8 af[4];
                #pragma unroll
                for (int mt = 0; mt < 4; ++mt)
                    af[mt] = *reinterpret_cast<const bf16x8*>(&Xa[(mt * 16 + l15) * 200 + kb * 32 + quad * 8]);
                #pragma unroll
                for (int nt = 0; nt < 3; ++nt) {
                    bf16x8 bf = *reinterpret_cast<const bf16x8*>(w2f + ((kb * 12 + ntg0 + nt) * 64 + lane) * 8);
                    #pragma unroll
                    for (int mt = 0; mt < 4; ++mt)
                        acc2[mt][nt] = MFMA16(af[mt], bf, acc2[mt][nt]);
                }
            }
            __syncthreads();   // B3 (all reads of Xa done)

            // ---- layer 2 GELU epilogue -> Xa (in place buffer reuse) ----
            #pragma unroll
            for (int nt = 0; nt < 3; ++nt) {
                int n = (ntg0 + nt) * 16 + l15;
                #pragma unroll
                for (int mt = 0; mt < 2; ++mt)
                    #pragma unroll
                    for (int i = 0; i < 4; ++i) {
                        float a = acc2[mt][nt][i] + b2r[nt];
                        float gv, dv; gelu_both(a, gv, dv);
                        Xa[(mt * 16 + quad * 4 + i) * 200 + n] = f2bf(gv);
                        Xa[((mt + 2) * 16 + quad * 4 + i) * 200 + n] = f2bf(dv * acc2[mt + 2][nt][i]);
                    }
            }
            __syncthreads();   // B4

            // ---- layer 3 + trace + RK4 state: wave 0 only (sole consumer) ----
            if (wave == 0) {
                f32x4 acc3[4] = {};
                #pragma unroll
                for (int kb = 0; kb < 6; ++kb)
                    #pragma unroll
                    for (int mt = 0; mt < 4; ++mt) {
                        bf16x8 af = *reinterpret_cast<const bf16x8*>(&Xa[(mt * 16 + l15) * 200 + kb * 32 + quad * 8]);
                        acc3[mt] = MFMA16(af, w3fr[kb], acc3[mt]);
                    }
                float Fc[2][4];
                #pragma unroll
                for (int mt = 0; mt < 2; ++mt)
                    #pragma unroll
                    for (int i = 0; i < 4; ++i) Fc[mt][i] = acc3[mt][i] + b3r;
                // Hutchinson trace: sum_d e[r][d] * Je[r][d], reduce over d = lane&15
                const float csub = (sub == 1 || sub == 2) ? 3.0f : 1.0f;
                #pragma unroll
                for (int mt = 0; mt < 2; ++mt)
                    #pragma unroll
                    for (int i = 0; i < 4; ++i) {
                        int r = mt * 16 + quad * 4 + i;
                        float p = ebf[r * 16 + l15] * acc3[mt + 2][i];
                        p += __shfl_xor(p, 1);
                        p += __shfl_xor(p, 2);
                        p += __shfl_xor(p, 4);
                        p += __shfl_xor(p, 8);
                        tracc[mt][i] += csub * p;
                    }
                if (sub == 0) {
                    #pragma unroll
                    for (int mt = 0; mt < 2; ++mt) for (int i = 0; i < 4; ++i) F1[mt][i] = Fc[mt][i];
                } else if (sub == 1) {
                    #pragma unroll
                    for (int mt = 0; mt < 2; ++mt) for (int i = 0; i < 4; ++i) F2[mt][i] = Fc[mt][i];
                } else if (sub == 2) {
                    #pragma unroll
                    for (int mt = 0; mt < 2; ++mt) for (int i = 0; i < 4; ++i) F3[mt][i] = Fc[mt][i];
                } else {
                    #pragma unroll
                    for (int mt = 0; mt < 2; ++mt)
                        #pragma unroll
                        for (int i = 0; i < 4; ++i)
                            yreg[mt][i] += DTc * 0.125f * (F1[mt][i] + 3.0f * (F2[mt][i] + F3[mt][i]) + Fc[mt][i]);
                }
            }
            __syncthreads();   // B5 (protects ebf/Xa for next stage)
        }
    }

    // ---- output: base - dlogp (wave 0) ----
    if (wave == 0) {
        #pragma unroll
        for (int mt = 0; mt < 2; ++mt)
            #pragma unroll
            for (int i = 0; i < 4; ++i) {
                float q = yreg[mt][i] * yreg[mt][i];
                q += __shfl_xor(q, 1);
                q += __shfl_xor(q, 2);
                q += __shfl_xor(q, 4);
                q += __shfl_xor(q, 8);
                if (l15 == 0)
                    out[r0 + mt * 16 + quad * 4 + i] =
                        -0.5f * q - 14.703016532f + DTc * 0.125f * tracc[mt][i];
            }
    }
}

extern "C" void kernel_launch(void* const* d_in, const int* in_sizes, int n_in,
                              void* d_out, int out_size, void* d_ws, size_t ws_size,
                              hipStream_t stream) {
    const float* theta = (const float*)d_in[0];
    const float* hctx  = (const float*)d_in[1];
    const float* eps   = (const float*)d_in[2];
    const float* W1    = (const float*)d_in[3];
    const float* b1    = (const float*)d_in[4];
    const float* W2    = (const float*)d_in[5];
    const float* b2    = (const float*)d_in[6];
    const float* W3    = (const float*)d_in[7];
    const float* b3    = (const float*)d_in[8];
    float* outp = (float*)d_out;

    unsigned short* w2f  = (unsigned short*)d_ws;   // 36864 elems
    unsigned short* w1yf = w2f + 36864;             // 6144
    unsigned short* w1cf = w1yf + 6144;             // 49152
    unsigned short* w3fg = w1cf + 49152;            // 3072

    hipLaunchKernelGGL(repack_kernel, dim3(47), dim3(256), 0, stream,
                       W1, W2, W3, w2f, w1yf, w1cf, w3fg);
    hipLaunchKernelGGL(cnf_mfma, dim3(512), dim3(256), 0, stream,
                       theta, hctx, eps, W1, b1, b2, b3, w2f, w1yf, w1cf, w3fg, outp);
}